// Round 14
// baseline (113.010 us; speedup 1.0000x reference)
//
#include <hip/hip_runtime.h>
#include <hip/hip_bf16.h>

// B=4, Q=K=512, D=512, H=256
#define HH 256
#define DD 512
#define MM 2048                       // B*Q == B*K flattened rows
#define CSCALE 2.8853900817779268f    // 2*log2(e), folded into W (linear)

typedef __bf16 bf16x8 __attribute__((ext_vector_type(8)));
typedef float floatx4 __attribute__((ext_vector_type(4)));

// ---------------------------------------------------------------------------
// prep (257 blocks — Xbf converter stage removed, R14):
//   blocks 0..255: transpose+scale Wq,Wk -> Wt[2][256][512] bf16
//   block 256: wv2 = -2*wv, sumW = sum(wv)
// ---------------------------------------------------------------------------
__global__ __launch_bounds__(256) void prep_kernel(
    const float* __restrict__ Wq, const float* __restrict__ Wk,
    const float* __restrict__ wv,
    __bf16* __restrict__ Wt, float* __restrict__ wv2, float* __restrict__ sumWp)
{
  const int bx = blockIdx.x;
  if (bx < 256) {
    const int mat  = bx >> 7;
    const int tile = bx & 127;
    const int kt = tile & 15;    // 512/32 k-tiles
    const int nt = tile >> 4;    // 256/32 n-tiles
    const float* __restrict__ W = mat ? Wk : Wq;
    __bf16* __restrict__ Wo = Wt + (size_t)mat * HH * DD;
    __shared__ float lds[32][33];
    const int i = threadIdx.x >> 5;   // 0..7
    const int j = threadIdx.x & 31;   // 0..31
    const int k0 = kt * 32, n0 = nt * 32;
#pragma unroll
    for (int p = 0; p < 4; ++p)
      lds[i + p * 8][j] = W[(k0 + i + p * 8) * HH + n0 + j];
    __syncthreads();
#pragma unroll
    for (int p = 0; p < 4; ++p) {
      const int n = i + p * 8;
      Wo[(n0 + n) * DD + k0 + j] = (__bf16)(lds[j][n] * CSCALE);
    }
  } else {
    __shared__ float red[256];
    const int t = threadIdx.x;
    float w = wv[t];
    wv2[t] = -2.0f * w;
    red[t] = w;
    __syncthreads();
    for (int s = 128; s > 0; s >>= 1) {
      if (t < s) red[t] += red[t + s];
      __syncthreads();
    }
    if (t == 0) *sumWp = red[0];
  }
}

// ---------------------------------------------------------------------------
// proj: P = X(2048x512 f32, inline cvt) @ Wt^T (bf16, prescaled by 2*log2e).
// Block = 4 waves: wave (tw, ks) computes 16x32 tile tw over K-half ks.
// LDS combine, then exp2 epilogue:
//   z==0: queries -> eq = exp2(qc) BF16 [2048][256]  (score unpacks; one
//         ds_read_b128 in score now serves TWO h-quads per q-row)
//   z==1: keys    -> ek = exp2(kc) BF16 [m/16][hq(64)][m%16][4]
//         (score reads all 32 hq of a half via IMMEDIATE offsets)
// Fragment layouts (HW-verified rounds 1-13):
//   A: lane A[m=lane&15][k=(lane>>4)*8+j]; B: B[k=(lane>>4)*8+j][n=lane&15]
//   D: reg i -> row=(lane>>4)*4+i, col=lane&15
// ---------------------------------------------------------------------------
__global__ __launch_bounds__(256, 4) void proj_kernel(
    const float* __restrict__ queries, const float* __restrict__ keys,
    const __bf16* __restrict__ Wt,
    __bf16* __restrict__ eqb, __bf16* __restrict__ ekb)
{
  const int w    = threadIdx.x >> 6;
  const int lane = threadIdx.x & 63;
  const int quad = lane >> 4;
  const int r    = lane & 15;
  const int tw = w & 1;        // which 16-row tile
  const int ks = w >> 1;       // which K half
  const bool is_k = (blockIdx.z != 0);
  const float* __restrict__ X  = is_k ? keys : queries;
  const __bf16* __restrict__ Wb = Wt + (is_k ? (size_t)HH * DD : 0);

  const int m0 = blockIdx.x * 32 + tw * 16;
  const int n0 = blockIdx.y * 32;

  floatx4 acc0 = {0.f, 0.f, 0.f, 0.f};
  floatx4 acc1 = {0.f, 0.f, 0.f, 0.f};
  const float*  arow = X + (size_t)(m0 + r) * DD + ks * 256 + quad * 8;
  const __bf16* b0   = Wb + (size_t)(n0 + r) * DD + ks * 256 + quad * 8;
  const __bf16* b1   = b0 + 16 * DD;

#pragma unroll
  for (int kk = 0; kk < 256; kk += 32) {
    float4 a0 = *(const float4*)(arow + kk);
    float4 a1 = *(const float4*)(arow + kk + 4);
    bf16x8 af;
    af[0] = (__bf16)a0.x; af[1] = (__bf16)a0.y;
    af[2] = (__bf16)a0.z; af[3] = (__bf16)a0.w;
    af[4] = (__bf16)a1.x; af[5] = (__bf16)a1.y;
    af[6] = (__bf16)a1.z; af[7] = (__bf16)a1.w;
    bf16x8 bf0 = *(const bf16x8*)(b0 + kk);
    bf16x8 bf1 = *(const bf16x8*)(b1 + kk);
    acc0 = __builtin_amdgcn_mfma_f32_16x16x32_bf16(af, bf0, acc0, 0, 0, 0);
    acc1 = __builtin_amdgcn_mfma_f32_16x16x32_bf16(af, bf1, acc1, 0, 0, 0);
  }

  __shared__ float part[2][64][9];   // +1 pad: conflict-free combine
  if (ks == 1) {
#pragma unroll
    for (int i = 0; i < 4; ++i) {
      part[tw][lane][i]     = acc0[i];
      part[tw][lane][4 + i] = acc1[i];
    }
  }
  __syncthreads();
  if (ks == 0) {
#pragma unroll
    for (int i = 0; i < 4; ++i) {
      acc0[i] += part[tw][lane][i];
      acc1[i] += part[tw][lane][4 + i];
    }
    const int mrow = m0 + quad * 4;
    if (!is_k) {
#pragma unroll
      for (int i = 0; i < 4; ++i) {
        eqb[(size_t)(mrow + i) * HH + n0 + r] =
            (__bf16)__builtin_amdgcn_exp2f(acc0[i]);
        eqb[(size_t)(mrow + i) * HH + n0 + 16 + r] =
            (__bf16)__builtin_amdgcn_exp2f(acc1[i]);
      }
    } else {
      const int na = n0 + r, nb = n0 + 16 + r;
#pragma unroll
      for (int i = 0; i < 4; ++i) {
        const int m = mrow + i;
        ekb[(((size_t)(m >> 4) * 64 + (na >> 2)) * 16 + (m & 15)) * 4 + (na & 3)] =
            (__bf16)__builtin_amdgcn_exp2f(acc0[i]);
        ekb[(((size_t)(m >> 4) * 64 + (nb >> 2)) * 16 + (m & 15)) * 4 + (nb & 3)] =
            (__bf16)__builtin_amdgcn_exp2f(acc1[i]);
      }
    }
  }
}

// ---------------------------------------------------------------------------
// score (R14): R10 structure (best measured), eq staged BF16 to cut the
// LDS-pipe load. Per-CU LDS model (fit R8: 6144 ops->38us, R10: 5120->32):
// was 5 b128/hq; now 1 w4 + 4 eq-b128 per TWO hq = 3/hq ->
// 3x32x32x12 = 15.4 us; VALU becomes binding (~20 us incl. +16 unpack/hq).
//   out[b,q,k] = sumW + sum_{quads} [n01*p23 + n23*p01] * rcp(p01*p23)
//   u_i = 1 + eq*ek; n01 = w'0*u1 + w'1*u0; w' = -2*wv  (exact tanh algebra)
// h-split 512-thr blocks (waves 0-3 h[0,128), 4-7 h[128,256)), LDS combine
// (no atomics — R9). TQ=4. Outer loop unroll-pinned (R12 spill lesson);
// live regs ~48 < 64 cap. Grid (2,128,4) = 1024 blocks -> 8 waves/SIMD.
// ---------------------------------------------------------------------------
__device__ __forceinline__ float bf_lo(unsigned u) {
  return __uint_as_float(u << 16);
}
__device__ __forceinline__ float bf_hi(unsigned u) {
  return __uint_as_float(u & 0xffff0000u);
}

__device__ __forceinline__ float quad_term(
    float ek0, float ek1, float ek2, float ek3,
    float e0, float e1, float e2, float e3,
    float4 w, float acc)
{
  float u0 = fmaf(e0, ek0, 1.0f);
  float u1 = fmaf(e1, ek1, 1.0f);
  float u2 = fmaf(e2, ek2, 1.0f);
  float u3 = fmaf(e3, ek3, 1.0f);
  float p01 = u0 * u1;
  float p23 = u2 * u3;
  float n01 = fmaf(w.y, u0, w.x * u1);
  float n23 = fmaf(w.w, u2, w.z * u3);
  float N   = fmaf(n23, p01, n01 * p23);
  float r   = __builtin_amdgcn_rcpf(p01 * p23);
  return fmaf(N, r, acc);
}

__global__ __launch_bounds__(512, 8) void score_kernel(
    const __bf16* __restrict__ eqb, const uint2* __restrict__ ekb,
    const float* __restrict__ wv2, const float* __restrict__ sumWp,
    float* __restrict__ out)
{
  __shared__ __align__(16) unsigned eqsu[2][4][64]; // [hb][q][h-pair] 2 KB
  __shared__ __align__(16) float wvs[2][128];       // 1 KB
  __shared__ __align__(16) float part[4][256];      // hb=1 partials 4 KB

  const int tid = threadIdx.x;
  const int t   = tid & 255;          // k lane
  const int hb  = tid >> 8;           // h half (wave-uniform: waves 0-3 / 4-7)
  const int b   = blockIdx.z;
  const int k   = blockIdx.x * 256 + t;
  const int q0  = blockIdx.y * 4;

  // Stage eq 4 rows x 256 h as bf16 pairs (2 KB) + wv2 (1 KB), coalesced.
  {
    const int q = tid >> 7;           // 0..3
    const int p = tid & 127;          // h-pair 0..127
    const unsigned* __restrict__ qrow =
        (const unsigned*)(eqb + (size_t)(b * 512 + q0 + q) * HH);
    eqsu[p >> 6][q][p & 63] = qrow[p];
    if (tid < 256) wvs[tid >> 7][tid & 127] = wv2[tid];
  }
  __syncthreads();

  const int m = b * 512 + k;          // global key row in [0,2048)
  const uint2* __restrict__ kptr =
      ekb + ((size_t)(m >> 4) * 64 + hb * 32) * 16 + (m & 15);

  float acc0 = 0.f, acc1 = 0.f, acc2 = 0.f, acc3 = 0.f;

#pragma unroll 1
  for (int c = 0; c < 16; ++c) {      // 16 chunks x 2 hq = 32 hq per half
    uint2 ka = kptr[(c * 2 + 0) * 16];      // imm-offset, <=3968
    uint2 kc = kptr[(c * 2 + 1) * 16];
    uint4 r0 = *(const uint4*)&eqsu[hb][0][c * 4];  // 8 bf16 = 2 hq
    uint4 r1 = *(const uint4*)&eqsu[hb][1][c * 4];
    uint4 r2 = *(const uint4*)&eqsu[hb][2][c * 4];
    uint4 r3 = *(const uint4*)&eqsu[hb][3][c * 4];
    float4 wa = *(const float4*)&wvs[hb][c * 8];
    float4 wb = *(const float4*)&wvs[hb][c * 8 + 4];
    // hq even
    {
      float p0 = bf_lo(ka.x), p1 = bf_hi(ka.x);
      float p2 = bf_lo(ka.y), p3 = bf_hi(ka.y);
      acc0 = quad_term(p0, p1, p2, p3,
                       bf_lo(r0.x), bf_hi(r0.x), bf_lo(r0.y), bf_hi(r0.y), wa, acc0);
      acc1 = quad_term(p0, p1, p2, p3,
                       bf_lo(r1.x), bf_hi(r1.x), bf_lo(r1.y), bf_hi(r1.y), wa, acc1);
      acc2 = quad_term(p0, p1, p2, p3,
                       bf_lo(r2.x), bf_hi(r2.x), bf_lo(r2.y), bf_hi(r2.y), wa, acc2);
      acc3 = quad_term(p0, p1, p2, p3,
                       bf_lo(r3.x), bf_hi(r3.x), bf_lo(r3.y), bf_hi(r3.y), wa, acc3);
    }
    // hq odd
    {
      float p0 = bf_lo(kc.x), p1 = bf_hi(kc.x);
      float p2 = bf_lo(kc.y), p3 = bf_hi(kc.y);
      acc0 = quad_term(p0, p1, p2, p3,
                       bf_lo(r0.z), bf_hi(r0.z), bf_lo(r0.w), bf_hi(r0.w), wb, acc0);
      acc1 = quad_term(p0, p1, p2, p3,
                       bf_lo(r1.z), bf_hi(r1.z), bf_lo(r1.w), bf_hi(r1.w), wb, acc1);
      acc2 = quad_term(p0, p1, p2, p3,
                       bf_lo(r2.z), bf_hi(r2.z), bf_lo(r2.w), bf_hi(r2.w), wb, acc2);
      acc3 = quad_term(p0, p1, p2, p3,
                       bf_lo(r3.z), bf_hi(r3.z), bf_lo(r3.w), bf_hi(r3.w), wb, acc3);
    }
  }

  if (hb == 1) {
    part[0][t] = acc0; part[1][t] = acc1;
    part[2][t] = acc2; part[3][t] = acc3;
  }
  __syncthreads();
  if (hb == 0) {
    const float sumW = *sumWp;
    float* obase = out + ((size_t)(b * 512 + q0)) * 512 + blockIdx.x * 256 + t;
    obase[0]    = sumW + acc0 + part[0][t];
    obase[512]  = sumW + acc1 + part[1][t];
    obase[1024] = sumW + acc2 + part[2][t];
    obase[1536] = sumW + acc3 + part[3][t];
  }
}

// ---------------------------------------------------------------------------
extern "C" void kernel_launch(void* const* d_in, const int* in_sizes, int n_in,
                              void* d_out, int out_size, void* d_ws, size_t ws_size,
                              hipStream_t stream) {
  (void)in_sizes; (void)n_in; (void)out_size; (void)ws_size;
  const float* queries = (const float*)d_in[0];
  const float* Keys    = (const float*)d_in[1];
  const float* Wq      = (const float*)d_in[2];
  const float* Wk      = (const float*)d_in[3];
  const float* wv      = (const float*)d_in[4];
  float* out = (float*)d_out;

  // ws layout (~3 MB of the 256 MB workspace):
  //   [0, 512K)      Wt   bf16 [2][256][512]
  //   [512K, +1K)    wv2  f32 [256]  (= -2*wv)
  //   [513K, +4)     sumW
  //   [1M, 2M)       eqb  bf16 [2048][256]
  //   [2M, 3M)       ekb  bf16 [m/16][64][16][4]
  char* ws = (char*)d_ws;
  __bf16* Wt    = (__bf16*)ws;
  float*  wv2   = (float*)(ws + (512 << 10));
  float*  sumWp = (float*)(ws + (513 << 10));
  __bf16* eqb   = (__bf16*)(ws + (1 << 20));
  __bf16* ekb   = (__bf16*)(ws + (2 << 20));

  prep_kernel<<<dim3(257), 256, 0, stream>>>(Wq, Wk, wv, Wt, wv2, sumWp);
  proj_kernel<<<dim3(64, 8, 2), 256, 0, stream>>>(queries, Keys, Wt, eqb, ekb);
  score_kernel<<<dim3(2, 128, 4), 512, 0, stream>>>(
      eqb, (const uint2*)ekb, wv2, sumWp, out);
}

// Round 15
// 111.615 us; speedup vs baseline: 1.0125x; 1.0125x over previous
//
#include <hip/hip_runtime.h>
#include <hip/hip_bf16.h>

// B=4, Q=K=512, D=512, H=256
#define HH 256
#define DD 512
#define MM 2048                       // B*Q == B*K flattened rows
#define CSCALE 2.8853900817779268f    // 2*log2(e), folded into W (linear)

typedef __bf16 bf16x8 __attribute__((ext_vector_type(8)));
typedef float floatx4 __attribute__((ext_vector_type(4)));

// ---------------------------------------------------------------------------
// prep (R10-proven): (a) blocks 0..255: transpose+scale Wq,Wk -> Wt bf16
//   (b) block 256: wv2 = -2*wv, sumW = sum(wv)
//   (c) blocks 257..1280: convert queries||keys f32 -> Xbf bf16
// ---------------------------------------------------------------------------
__global__ __launch_bounds__(256) void prep_kernel(
    const float* __restrict__ Wq, const float* __restrict__ Wk,
    const float* __restrict__ wv,
    const float* __restrict__ queries, const float* __restrict__ keys,
    __bf16* __restrict__ Wt, __bf16* __restrict__ Xbf,
    float* __restrict__ wv2, float* __restrict__ sumWp)
{
  const int bx = blockIdx.x;
  if (bx < 256) {
    const int mat  = bx >> 7;
    const int tile = bx & 127;
    const int kt = tile & 15;    // 512/32 k-tiles
    const int nt = tile >> 4;    // 256/32 n-tiles
    const float* __restrict__ W = mat ? Wk : Wq;
    __bf16* __restrict__ Wo = Wt + (size_t)mat * HH * DD;
    __shared__ float lds[32][33];
    const int i = threadIdx.x >> 5;   // 0..7
    const int j = threadIdx.x & 31;   // 0..31
    const int k0 = kt * 32, n0 = nt * 32;
#pragma unroll
    for (int p = 0; p < 4; ++p)
      lds[i + p * 8][j] = W[(k0 + i + p * 8) * HH + n0 + j];
    __syncthreads();
#pragma unroll
    for (int p = 0; p < 4; ++p) {
      const int n = i + p * 8;
      Wo[(n0 + n) * DD + k0 + j] = (__bf16)(lds[j][n] * CSCALE);
    }
  } else if (bx == 256) {
    __shared__ float red[256];
    const int t = threadIdx.x;
    float w = wv[t];
    wv2[t] = -2.0f * w;
    red[t] = w;
    __syncthreads();
    for (int s = 128; s > 0; s >>= 1) {
      if (t < s) red[t] += red[t + s];
      __syncthreads();
    }
    if (t == 0) *sumWp = red[0];
  } else {
    const int blk = bx - 257;                       // 0..1023
    const size_t dst = (size_t)blk * 2048 + threadIdx.x * 8;
    const float* __restrict__ src =
        (blk < 512) ? (queries + dst) : (keys + dst - (size_t)1048576);
    float4 a = *(const float4*)(src);
    float4 b = *(const float4*)(src + 4);
    bf16x8 v;
    v[0] = (__bf16)a.x; v[1] = (__bf16)a.y; v[2] = (__bf16)a.z; v[3] = (__bf16)a.w;
    v[4] = (__bf16)b.x; v[5] = (__bf16)b.y; v[6] = (__bf16)b.z; v[7] = (__bf16)b.w;
    *(bf16x8*)(Xbf + dst) = v;
  }
}

// ---------------------------------------------------------------------------
// proj (R10 body + R14 epilogue): P = Xbf(bf16) @ Wt^T (bf16, prescaled).
// Block = 4 waves: wave (tw, ks) computes 16x32 tile tw over K-half ks.
// LDS combine, then exp2 epilogue:
//   z==0: queries -> eq = exp2(qc) BF16 [2048][256] (score: 1 b128 = 2 hq)
//   z==1: keys    -> ek = exp2(kc) BF16 [m/16][hq(64)][m%16][4]
//         (score reads all 32 hq of a half via IMMEDIATE offsets)
// Fragment layouts (HW-verified rounds 1-14):
//   A: lane A[m=lane&15][k=(lane>>4)*8+j]; B: B[k=(lane>>4)*8+j][n=lane&15]
//   D: reg i -> row=(lane>>4)*4+i, col=lane&15
// ---------------------------------------------------------------------------
__global__ __launch_bounds__(256, 4) void proj_kernel(
    const __bf16* __restrict__ Xbf, const __bf16* __restrict__ Wt,
    __bf16* __restrict__ eqb, __bf16* __restrict__ ekb)
{
  const int w    = threadIdx.x >> 6;
  const int lane = threadIdx.x & 63;
  const int quad = lane >> 4;
  const int r    = lane & 15;
  const int tw = w & 1;        // which 16-row tile
  const int ks = w >> 1;       // which K half
  const bool is_k = (blockIdx.z != 0);
  const __bf16* __restrict__ X  = Xbf + (is_k ? (size_t)1048576 : 0);
  const __bf16* __restrict__ Wb = Wt + (is_k ? (size_t)HH * DD : 0);

  const int m0 = blockIdx.x * 32 + tw * 16;
  const int n0 = blockIdx.y * 32;

  floatx4 acc0 = {0.f, 0.f, 0.f, 0.f};
  floatx4 acc1 = {0.f, 0.f, 0.f, 0.f};
  const __bf16* arow = X + (size_t)(m0 + r) * DD + ks * 256 + quad * 8;
  const __bf16* b0   = Wb + (size_t)(n0 + r) * DD + ks * 256 + quad * 8;
  const __bf16* b1   = b0 + 16 * DD;

#pragma unroll
  for (int kk = 0; kk < 256; kk += 32) {
    bf16x8 af  = *(const bf16x8*)(arow + kk);
    bf16x8 bf0 = *(const bf16x8*)(b0 + kk);
    bf16x8 bf1 = *(const bf16x8*)(b1 + kk);
    acc0 = __builtin_amdgcn_mfma_f32_16x16x32_bf16(af, bf0, acc0, 0, 0, 0);
    acc1 = __builtin_amdgcn_mfma_f32_16x16x32_bf16(af, bf1, acc1, 0, 0, 0);
  }

  __shared__ float part[2][64][9];   // +1 pad: conflict-free combine
  if (ks == 1) {
#pragma unroll
    for (int i = 0; i < 4; ++i) {
      part[tw][lane][i]     = acc0[i];
      part[tw][lane][4 + i] = acc1[i];
    }
  }
  __syncthreads();
  if (ks == 0) {
#pragma unroll
    for (int i = 0; i < 4; ++i) {
      acc0[i] += part[tw][lane][i];
      acc1[i] += part[tw][lane][4 + i];
    }
    const int mrow = m0 + quad * 4;
    if (!is_k) {
#pragma unroll
      for (int i = 0; i < 4; ++i) {
        eqb[(size_t)(mrow + i) * HH + n0 + r] =
            (__bf16)__builtin_amdgcn_exp2f(acc0[i]);
        eqb[(size_t)(mrow + i) * HH + n0 + 16 + r] =
            (__bf16)__builtin_amdgcn_exp2f(acc1[i]);
      }
    } else {
      const int na = n0 + r, nb = n0 + 16 + r;
#pragma unroll
      for (int i = 0; i < 4; ++i) {
        const int m = mrow + i;
        ekb[(((size_t)(m >> 4) * 64 + (na >> 2)) * 16 + (m & 15)) * 4 + (na & 3)] =
            (__bf16)__builtin_amdgcn_exp2f(acc0[i]);
        ekb[(((size_t)(m >> 4) * 64 + (nb >> 2)) * 16 + (m & 15)) * 4 + (nb & 3)] =
            (__bf16)__builtin_amdgcn_exp2f(acc1[i]);
      }
    }
  }
}

// ---------------------------------------------------------------------------
// score (R14's, kept): R10 structure with eq staged BF16 — 3 LDS ops/hq
// (was 5). Per-CU pipe model: LDS 3x32x32x12 = 15.4 us; VALU ~16.2 us
// (incl. unpack) is now binding.
//   out[b,q,k] = sumW + sum_{quads} [n01*p23 + n23*p01] * rcp(p01*p23)
//   u_i = 1 + eq*ek; n01 = w'0*u1 + w'1*u0; w' = -2*wv  (exact tanh algebra)
// h-split 512-thr blocks, LDS combine (no atomics — R9), TQ=4, outer loop
// unroll-pinned (R12 spill lesson). Grid (2,128,4) -> 8 waves/SIMD.
// ---------------------------------------------------------------------------
__device__ __forceinline__ float bf_lo(unsigned u) {
  return __uint_as_float(u << 16);
}
__device__ __forceinline__ float bf_hi(unsigned u) {
  return __uint_as_float(u & 0xffff0000u);
}

__device__ __forceinline__ float quad_term(
    float ek0, float ek1, float ek2, float ek3,
    float e0, float e1, float e2, float e3,
    float4 w, float acc)
{
  float u0 = fmaf(e0, ek0, 1.0f);
  float u1 = fmaf(e1, ek1, 1.0f);
  float u2 = fmaf(e2, ek2, 1.0f);
  float u3 = fmaf(e3, ek3, 1.0f);
  float p01 = u0 * u1;
  float p23 = u2 * u3;
  float n01 = fmaf(w.y, u0, w.x * u1);
  float n23 = fmaf(w.w, u2, w.z * u3);
  float N   = fmaf(n23, p01, n01 * p23);
  float r   = __builtin_amdgcn_rcpf(p01 * p23);
  return fmaf(N, r, acc);
}

__global__ __launch_bounds__(512, 8) void score_kernel(
    const __bf16* __restrict__ eqb, const uint2* __restrict__ ekb,
    const float* __restrict__ wv2, const float* __restrict__ sumWp,
    float* __restrict__ out)
{
  __shared__ __align__(16) unsigned eqsu[2][4][64]; // [hb][q][h-pair] 2 KB
  __shared__ __align__(16) float wvs[2][128];       // 1 KB
  __shared__ __align__(16) float part[4][256];      // hb=1 partials 4 KB

  const int tid = threadIdx.x;
  const int t   = tid & 255;          // k lane
  const int hb  = tid >> 8;           // h half (wave-uniform: waves 0-3 / 4-7)
  const int b   = blockIdx.z;
  const int k   = blockIdx.x * 256 + t;
  const int q0  = blockIdx.y * 4;

  // Stage eq 4 rows x 256 h as bf16 pairs (2 KB) + wv2 (1 KB), coalesced.
  {
    const int q = tid >> 7;           // 0..3
    const int p = tid & 127;          // h-pair 0..127
    const unsigned* __restrict__ qrow =
        (const unsigned*)(eqb + (size_t)(b * 512 + q0 + q) * HH);
    eqsu[p >> 6][q][p & 63] = qrow[p];
    if (tid < 256) wvs[tid >> 7][tid & 127] = wv2[tid];
  }
  __syncthreads();

  const int m = b * 512 + k;          // global key row in [0,2048)
  const uint2* __restrict__ kptr =
      ekb + ((size_t)(m >> 4) * 64 + hb * 32) * 16 + (m & 15);

  float acc0 = 0.f, acc1 = 0.f, acc2 = 0.f, acc3 = 0.f;

#pragma unroll 1
  for (int c = 0; c < 16; ++c) {      // 16 chunks x 2 hq = 32 hq per half
    uint2 ka = kptr[(c * 2 + 0) * 16];      // imm-offset, <=3968
    uint2 kc = kptr[(c * 2 + 1) * 16];
    uint4 r0 = *(const uint4*)&eqsu[hb][0][c * 4];  // 8 bf16 = 2 hq
    uint4 r1 = *(const uint4*)&eqsu[hb][1][c * 4];
    uint4 r2 = *(const uint4*)&eqsu[hb][2][c * 4];
    uint4 r3 = *(const uint4*)&eqsu[hb][3][c * 4];
    float4 wa = *(const float4*)&wvs[hb][c * 8];
    float4 wb = *(const float4*)&wvs[hb][c * 8 + 4];
    // hq even
    {
      float p0 = bf_lo(ka.x), p1 = bf_hi(ka.x);
      float p2 = bf_lo(ka.y), p3 = bf_hi(ka.y);
      acc0 = quad_term(p0, p1, p2, p3,
                       bf_lo(r0.x), bf_hi(r0.x), bf_lo(r0.y), bf_hi(r0.y), wa, acc0);
      acc1 = quad_term(p0, p1, p2, p3,
                       bf_lo(r1.x), bf_hi(r1.x), bf_lo(r1.y), bf_hi(r1.y), wa, acc1);
      acc2 = quad_term(p0, p1, p2, p3,
                       bf_lo(r2.x), bf_hi(r2.x), bf_lo(r2.y), bf_hi(r2.y), wa, acc2);
      acc3 = quad_term(p0, p1, p2, p3,
                       bf_lo(r3.x), bf_hi(r3.x), bf_lo(r3.y), bf_hi(r3.y), wa, acc3);
    }
    // hq odd
    {
      float p0 = bf_lo(kc.x), p1 = bf_hi(kc.x);
      float p2 = bf_lo(kc.y), p3 = bf_hi(kc.y);
      acc0 = quad_term(p0, p1, p2, p3,
                       bf_lo(r0.z), bf_hi(r0.z), bf_lo(r0.w), bf_hi(r0.w), wb, acc0);
      acc1 = quad_term(p0, p1, p2, p3,
                       bf_lo(r1.z), bf_hi(r1.z), bf_lo(r1.w), bf_hi(r1.w), wb, acc1);
      acc2 = quad_term(p0, p1, p2, p3,
                       bf_lo(r2.z), bf_hi(r2.z), bf_lo(r2.w), bf_hi(r2.w), wb, acc2);
      acc3 = quad_term(p0, p1, p2, p3,
                       bf_lo(r3.z), bf_hi(r3.z), bf_lo(r3.w), bf_hi(r3.w), wb, acc3);
    }
  }

  if (hb == 1) {
    part[0][t] = acc0; part[1][t] = acc1;
    part[2][t] = acc2; part[3][t] = acc3;
  }
  __syncthreads();
  if (hb == 0) {
    const float sumW = *sumWp;
    float* obase = out + ((size_t)(b * 512 + q0)) * 512 + blockIdx.x * 256 + t;
    obase[0]    = sumW + acc0 + part[0][t];
    obase[512]  = sumW + acc1 + part[1][t];
    obase[1024] = sumW + acc2 + part[2][t];
    obase[1536] = sumW + acc3 + part[3][t];
  }
}

// ---------------------------------------------------------------------------
extern "C" void kernel_launch(void* const* d_in, const int* in_sizes, int n_in,
                              void* d_out, int out_size, void* d_ws, size_t ws_size,
                              hipStream_t stream) {
  (void)in_sizes; (void)n_in; (void)out_size; (void)ws_size;
  const float* queries = (const float*)d_in[0];
  const float* Keys    = (const float*)d_in[1];
  const float* Wq      = (const float*)d_in[2];
  const float* Wk      = (const float*)d_in[3];
  const float* wv      = (const float*)d_in[4];
  float* out = (float*)d_out;

  // ws layout (~7 MB of the 256 MB workspace):
  //   [0, 512K)      Wt   bf16 [2][256][512]
  //   [512K, +1K)    wv2  f32 [256]  (= -2*wv)
  //   [513K, +4)     sumW
  //   [1M, 5M)       Xbf  bf16 [2][2048][512]  (queries||keys, converted)
  //   [5M, 6M)       eqb  bf16 [2048][256]
  //   [6M, 7M)       ekb  bf16 [m/16][64][16][4]
  char* ws = (char*)d_ws;
  __bf16* Wt    = (__bf16*)ws;
  float*  wv2   = (float*)(ws + (512 << 10));
  float*  sumWp = (float*)(ws + (513 << 10));
  __bf16* Xbf   = (__bf16*)(ws + (1 << 20));
  __bf16* eqb   = (__bf16*)(ws + (5ull << 20));
  __bf16* ekb   = (__bf16*)(ws + (6ull << 20));

  prep_kernel<<<dim3(1281), 256, 0, stream>>>(
      Wq, Wk, wv, queries, Keys, Wt, Xbf, wv2, sumWp);
  proj_kernel<<<dim3(64, 8, 2), 256, 0, stream>>>(Xbf, Wt, eqb, ekb);
  score_kernel<<<dim3(2, 128, 4), 512, 0, stream>>>(
      eqb, (const uint2*)ekb, wv2, sumWp, out);
}